// Round 5
// baseline (941.652 us; speedup 1.0000x reference)
//
#include <hip/hip_runtime.h>
#include <stdint.h>

typedef float f2 __attribute__((ext_vector_type(2)));
typedef float f4 __attribute__((ext_vector_type(4)));

// res[l] = floor(16 * b^l), b = exp((ln512 - ln16)/15) in fp32.
__constant__ float c_res[16] = {16.f, 20.f, 25.f, 32.f, 40.f, 50.f, 64.f, 80.f,
                                101.f, 128.f, 161.f, 203.f, 256.f, 322.f, 406.f, 512.f};

#define HASH_MASK ((1u << 19) - 1u)
#define P1 2654435761u
#define P2 805459861u
#define PTS_PER_THREAD 2
#define N_DENSE 7

// Dense de-hashed tables for levels 0..6. Dim D = res+2 (corner coords go up
// to res+1). Cell = f4 holding entries (z, z+1) -> one aligned 16B load gives
// both z-corners; 4 loads cover all 8 corners.
__constant__ uint32_t c_D[N_DENSE]    = {18, 22, 27, 34, 42, 52, 66};
__constant__ uint32_t c_doff[N_DENSE] = {0, 5832, 16480, 36163, 75467, 149555, 290163};
#define DENSE_TOTAL 577659u            // sum of D^3, in f4 cells (9.24 MB)

__global__ __launch_bounds__(256) void build_dense_kernel(
    const float* __restrict__ tables, f4* __restrict__ dense)
{
    uint32_t t = blockIdx.x * 256 + threadIdx.x;
    if (t >= DENSE_TOTAL) return;
    int l = 0;
    #pragma unroll
    for (int i = 1; i < N_DENSE; ++i) if (t >= c_doff[i]) l = i;
    uint32_t local = t - c_doff[l];
    uint32_t D = c_D[l];
    uint32_t cz = local % D;
    uint32_t tmp = local / D;
    uint32_t cy = tmp % D;
    uint32_t cx = tmp / D;
    const f2* __restrict__ tab = (const f2*)tables + ((size_t)l << 19);
    uint32_t h0 = (cx ^ (cy * P1) ^ (cz * P2)) & HASH_MASK;
    uint32_t h1 = (cx ^ (cy * P1) ^ ((cz + 1u) * P2)) & HASH_MASK;
    f2 a = tab[h0];
    f2 b = tab[h1];
    f4 v = {a.x, a.y, b.x, b.y};
    dense[t] = v;
}

// Grid: 2 phases (levels 0-7, 8-15) x chunks x 8 levels; blockIdx%8 == level%8
// pins one level's table per XCD L2 (round-robin dispatch); phase split keeps
// levels l and l+8 from being live together.
__global__ __launch_bounds__(256) void hash_encode_kernel(
    const float* __restrict__ x,
    const float* __restrict__ tables,
    const f4* __restrict__ dense,
    float* __restrict__ out,
    float* __restrict__ mask_out,
    int n_points,
    int blocks_per_phase,
    int n_dense)              // 0 (ws too small) or N_DENSE
{
    int bid = blockIdx.x;
    int level_base = 0;
    if (bid >= blocks_per_phase) { bid -= blocks_per_phase; level_base = 8; }
    int level = (bid & 7) + level_base;
    int chunk = bid >> 3;

    float res  = c_res[level];
    float grid = 1.0f / res;

    int pbase = chunk * (256 * PTS_PER_THREAD) + threadIdx.x;

    float wx[PTS_PER_THREAD], wy[PTS_PER_THREAD], wz[PTS_PER_THREAD];
    uint32_t bx[PTS_PER_THREAD], by[PTS_PER_THREAD], bz[PTS_PER_THREAD];
    bool valid[PTS_PER_THREAD];
    int pp[PTS_PER_THREAD];

    #pragma unroll
    for (int s = 0; s < PTS_PER_THREAD; ++s) {
        int p = pbase + s * 256;
        pp[s] = p;
        valid[s] = (p < n_points);
        int pc = valid[s] ? p : 0;

        float x0 = __builtin_nontemporal_load(&x[3 * (size_t)pc + 0]);
        float x1 = __builtin_nontemporal_load(&x[3 * (size_t)pc + 1]);
        float x2 = __builtin_nontemporal_load(&x[3 * (size_t)pc + 2]);

        if (level == 0 && valid[s]) {
            bool keep = (x0 >= 0.f) & (x0 <= 1.f) &
                        (x1 >= 0.f) & (x1 <= 1.f) &
                        (x2 >= 0.f) & (x2 <= 1.f);
            __builtin_nontemporal_store(keep ? 1.0f : 0.0f, &mask_out[pc]);
        }

        x0 = fminf(fmaxf(x0, 0.f), 1.f);
        x1 = fminf(fmaxf(x1, 0.f), 1.f);
        x2 = fminf(fmaxf(x2, 0.f), 1.f);

        float b0 = floorf(x0 / grid);
        float b1 = floorf(x1 / grid);
        float b2 = floorf(x2 / grid);

        wx[s] = (x0 - b0 * grid) / grid;
        wy[s] = (x1 - b1 * grid) / grid;
        wz[s] = (x2 - b2 * grid) / grid;

        bx[s] = (uint32_t)b0;
        by[s] = (uint32_t)b1;
        bz[s] = (uint32_t)b2;
    }

    if (level < n_dense) {
        // ---- dense path: 4 aligned 16B loads per point ----
        uint32_t D = c_D[level];
        const f4* __restrict__ dl = dense + c_doff[level];

        f4 a00[PTS_PER_THREAD], a01[PTS_PER_THREAD],
           a10[PTS_PER_THREAD], a11[PTS_PER_THREAD];
        #pragma unroll
        for (int s = 0; s < PTS_PER_THREAD; ++s) {
            uint32_t base = (bx[s] * D + by[s]) * D + bz[s];
            uint32_t DD = D * D;
            a00[s] = dl[base];
            a01[s] = dl[base + D];
            a10[s] = dl[base + DD];
            a11[s] = dl[base + DD + D];
        }
        #pragma unroll
        for (int s = 0; s < PTS_PER_THREAD; ++s) {
            float owx = 1.f - wx[s], owy = 1.f - wy[s], owz = 1.f - wz[s];
            // m.xy = z0-corner lerped over x, m.zw = z1-corner lerped over x
            f4 m0 = a00[s] * owx + a10[s] * wx[s];
            f4 m1 = a01[s] * owx + a11[s] * wx[s];
            f4 n  = m0 * owy + m1 * wy[s];
            f2 cv;
            cv.x = n.x * owz + n.z * wz[s];
            cv.y = n.y * owz + n.w * wz[s];
            if (valid[s]) {
                f2* dst = (f2*)(out + (size_t)pp[s] * 32) + level;
                __builtin_nontemporal_store(cv, dst);
            }
        }
    } else {
        // ---- hash path: 8 random 8B gathers per point ----
        const f2* __restrict__ tab =
            (const f2*)tables + ((size_t)level << 19);

        uint32_t idx[PTS_PER_THREAD][8];
        #pragma unroll
        for (int s = 0; s < PTS_PER_THREAD; ++s) {
            uint32_t hx0 = bx[s];          uint32_t hx1 = hx0 + 1u;
            uint32_t hy0 = by[s] * P1;     uint32_t hy1 = hy0 + P1;
            uint32_t hz0 = bz[s] * P2;     uint32_t hz1 = hz0 + P2;
            idx[s][0] = (hx0 ^ hy0 ^ hz0) & HASH_MASK;
            idx[s][1] = (hx0 ^ hy0 ^ hz1) & HASH_MASK;
            idx[s][2] = (hx0 ^ hy1 ^ hz0) & HASH_MASK;
            idx[s][3] = (hx0 ^ hy1 ^ hz1) & HASH_MASK;
            idx[s][4] = (hx1 ^ hy0 ^ hz0) & HASH_MASK;
            idx[s][5] = (hx1 ^ hy0 ^ hz1) & HASH_MASK;
            idx[s][6] = (hx1 ^ hy1 ^ hz0) & HASH_MASK;
            idx[s][7] = (hx1 ^ hy1 ^ hz1) & HASH_MASK;
        }
        f2 e[PTS_PER_THREAD][8];
        #pragma unroll
        for (int s = 0; s < PTS_PER_THREAD; ++s)
            #pragma unroll
            for (int c = 0; c < 8; ++c)
                e[s][c] = tab[idx[s][c]];

        #pragma unroll
        for (int s = 0; s < PTS_PER_THREAD; ++s) {
            float owx = 1.f - wx[s], owy = 1.f - wy[s], owz = 1.f - wz[s];
            f2 c00 = e[s][0] * owx + e[s][4] * wx[s];
            f2 c01 = e[s][1] * owx + e[s][5] * wx[s];
            f2 c10 = e[s][2] * owx + e[s][6] * wx[s];
            f2 c11 = e[s][3] * owx + e[s][7] * wx[s];
            f2 c0 = c00 * owy + c10 * wy[s];
            f2 c1 = c01 * owy + c11 * wy[s];
            f2 cv = c0 * owz + c1 * wz[s];
            if (valid[s]) {
                f2* dst = (f2*)(out + (size_t)pp[s] * 32) + level;
                __builtin_nontemporal_store(cv, dst);
            }
        }
    }
}

extern "C" void kernel_launch(void* const* d_in, const int* in_sizes, int n_in,
                              void* d_out, int out_size, void* d_ws, size_t ws_size,
                              hipStream_t stream) {
    const float* x      = (const float*)d_in[0];
    const float* tables = (const float*)d_in[1];
    float* out = (float*)d_out;
    int n_points = in_sizes[0] / 3;
    float* mask_out = out + (size_t)n_points * 32;

    f4* dense = (f4*)d_ws;
    int n_dense = (ws_size >= (size_t)DENSE_TOTAL * 16) ? N_DENSE : 0;

    if (n_dense) {
        int bblocks = (DENSE_TOTAL + 255) / 256;
        hipLaunchKernelGGL(build_dense_kernel, dim3(bblocks), dim3(256), 0, stream,
                           tables, dense);
    }

    int chunks = (n_points + 256 * PTS_PER_THREAD - 1) / (256 * PTS_PER_THREAD);
    int blocks_per_phase = chunks * 8;
    int blocks = blocks_per_phase * 2;
    hipLaunchKernelGGL(hash_encode_kernel, dim3(blocks), dim3(256), 0, stream,
                       x, tables, dense, out, mask_out, n_points,
                       blocks_per_phase, n_dense);
}